// Round 7
// baseline (271.940 us; speedup 1.0000x reference)
//
#include <hip/hip_runtime.h>
#include <math.h>

#define P_NUM 8192
#define E_NUM 4194304
#define EPT 4

#define FOV_H 2.0943951f

typedef float f32x4 __attribute__((ext_vector_type(4)));
typedef int   i32x4 __attribute__((ext_vector_type(4)));

// ---------- prep A: precompute cartesian (vx,vy,vz) per patch entry ----------
// 12-byte exact records; also emits the elev residual.
__global__ __launch_bounds__(256) void fuse_prep(const float* __restrict__ patch_coords,
                                                 const float* __restrict__ elev,
                                                 const float* __restrict__ init_elev,
                                                 f32x4* __restrict__ table,  // 3*f32x4 per 4 edges
                                                 float* __restrict__ out) {
    const int tid = blockIdx.x * blockDim.x + threadIdx.x;   // [0, E_NUM/4)
    const f32x4 a  = __builtin_nontemporal_load((const f32x4*)patch_coords + 2 * tid);
    const f32x4 b  = __builtin_nontemporal_load((const f32x4*)patch_coords + 2 * tid + 1);
    const f32x4 e  = __builtin_nontemporal_load((const f32x4*)elev + tid);
    const f32x4 ie = __builtin_nontemporal_load((const f32x4*)init_elev + tid);

    const float rr[4] = {a.x, a.z, b.x, b.z};
    const float th[4] = {a.y, a.w, b.y, b.w};
    const float ph[4] = {e.x, e.y, e.z, e.w};
    float v[12];
#pragma unroll
    for (int k = 0; k < 4; ++k) {
        // EXACT same fp32 expressions the main kernel used -> bit-identical
        const float cp = cosf(ph[k]), sph = sinf(ph[k]);
        const float ct = cosf(th[k]), sth = sinf(th[k]);
        v[3 * k + 0] = rr[k] * cp * ct;
        v[3 * k + 1] = rr[k] * cp * sth;
        v[3 * k + 2] = rr[k] * sph;
    }
    // 48 contiguous bytes per thread, 16-B aligned
    table[3 * tid + 0] = (f32x4){v[0], v[1], v[2],  v[3]};
    table[3 * tid + 1] = (f32x4){v[4], v[5], v[6],  v[7]};
    table[3 * tid + 2] = (f32x4){v[8], v[9], v[10], v[11]};

    const f32x4 er = {e.x - ie.x, e.y - ie.y, e.z - ie.z, e.w - ie.w};
    __builtin_nontemporal_store(er, (f32x4*)(out + 2 * E_NUM + 7 * P_NUM) + tid);
}

// ---------- prep B: pad poses 7->8 floats + pose residual ----------
__global__ __launch_bounds__(256) void pose_prep(const float* __restrict__ poses,
                                                 const float* __restrict__ init_poses,
                                                 f32x4* __restrict__ pose8,
                                                 float* __restrict__ out) {
    const int tid = blockIdx.x * blockDim.x + threadIdx.x;   // [0, 14336)
    if (tid < P_NUM) {
        const float* s = poses + 7 * tid;
        pose8[2 * tid]     = (f32x4){s[0], s[1], s[2], s[3]};  // tx ty tz qx
        pose8[2 * tid + 1] = (f32x4){s[4], s[5], s[6], 0.0f};  // qy qz qw pad
    }
    if (tid < (7 * P_NUM) / 4) {
        const f32x4 a = ((const f32x4*)poses)[tid];
        const f32x4 b = ((const f32x4*)init_poses)[tid];
        const f32x4 r = {a.x - b.x, a.y - b.y, a.z - b.z, a.w - b.w};
        __builtin_nontemporal_store(r, (f32x4*)(out + 2 * E_NUM) + tid);
    }
}

__device__ __forceinline__ void quatrot(float ux, float uy, float uz, float uw,
                                        float vx, float vy, float vz,
                                        float& ox, float& oy, float& oz) {
    float tqx = 2.0f * (uy * vz - uz * vy);
    float tqy = 2.0f * (uz * vx - ux * vz);
    float tqz = 2.0f * (ux * vy - uy * vx);
    ox = vx + uw * tqx + (uy * tqz - uz * tqy);
    oy = vy + uw * tqy + (uz * tqx - ux * tqz);
    oz = vz + uw * tqz + (ux * tqy - uy * tqx);
}

__global__ __launch_bounds__(256) void ba_main(
    const float* __restrict__ table,   // E_NUM x 12B (vx,vy,vz), ws
    const f32x4* __restrict__ pose8,   // ws
    const float* __restrict__ target,  // E_NUM*2
    const int*   __restrict__ src_idx,
    const int*   __restrict__ tgt_idx,
    const int*   __restrict__ patch_idx,
    float*       __restrict__ out)
{
    const int tid = blockIdx.x * blockDim.x + threadIdx.x;  // [0, E_NUM/EPT)

    const float R_RANGE = 30.0f - 0.5f;
    const float BINS    = 512.0f;
    const float BEAMS   = 512.0f;

    const i32x4 s4 = __builtin_nontemporal_load((const i32x4*)src_idx + tid);
    const i32x4 t4 = __builtin_nontemporal_load((const i32x4*)tgt_idx + tid);
    const i32x4 p4 = __builtin_nontemporal_load((const i32x4*)patch_idx + tid);
    const int si[EPT] = {s4.x, s4.y, s4.z, s4.w};
    const int ti[EPT] = {t4.x, t4.y, t4.z, t4.w};
    const int pi[EPT] = {p4.x, p4.y, p4.z, p4.w};

    // ---- issue all gathers up front ----
    float vx[EPT], vy[EPT], vz[EPT];
    f32x4 slo[EPT], shi[EPT], tlo[EPT], thi[EPT];
#pragma unroll
    for (int e = 0; e < EPT; ++e) {
        const float* rp = table + 3u * (unsigned)pi[e];
        vx[e] = rp[0]; vy[e] = rp[1]; vz[e] = rp[2];
        slo[e] = pose8[2 * si[e]];
        shi[e] = pose8[2 * si[e] + 1];
        tlo[e] = pose8[2 * ti[e]];
        thi[e] = pose8[2 * ti[e] + 1];
    }

    const f32x4 tg01 = __builtin_nontemporal_load((const f32x4*)target + 2 * tid);
    const f32x4 tg23 = __builtin_nontemporal_load((const f32x4*)target + 2 * tid + 1);
    const float tgr[EPT]  = {tg01.x, tg01.z, tg23.x, tg23.z};
    const float tgth[EPT] = {tg01.y, tg01.w, tg23.y, tg23.w};

    float res[2 * EPT];
#pragma unroll
    for (int e = 0; e < EPT; ++e) {
        float gx, gy, gz;
        quatrot(slo[e].w, shi[e].x, shi[e].y, shi[e].z, vx[e], vy[e], vz[e], gx, gy, gz);
        gx += slo[e].x; gy += slo[e].y; gz += slo[e].z;

        float lx, ly, lz;
        quatrot(-tlo[e].w, -thi[e].x, -thi[e].y, thi[e].z,
                gx - tlo[e].x, gy - tlo[e].y, gz - tlo[e].z, lx, ly, lz);

        const float rr  = sqrtf(lx * lx + ly * ly + lz * lz);
        const float tth = atan2f(ly, lx);
        res[2 * e]     = (rr  - tgr[e])  / R_RANGE * BINS;
        res[2 * e + 1] = (tth - tgth[e]) / FOV_H * BEAMS;
    }

    const f32x4 o0 = {res[0], res[1], res[2], res[3]};
    const f32x4 o1 = {res[4], res[5], res[6], res[7]};
    __builtin_nontemporal_store(o0, (f32x4*)out + 2 * tid);
    __builtin_nontemporal_store(o1, (f32x4*)out + 2 * tid + 1);
}

extern "C" void kernel_launch(void* const* d_in, const int* in_sizes, int n_in,
                              void* d_out, int out_size, void* d_ws, size_t ws_size,
                              hipStream_t stream) {
    const float* poses        = (const float*)d_in[0];
    const float* init_poses   = (const float*)d_in[1];
    const float* patch_coords = (const float*)d_in[2];
    const float* elev         = (const float*)d_in[3];
    const float* init_elev    = (const float*)d_in[4];
    const float* target       = (const float*)d_in[5];
    const int*   src_idx      = (const int*)d_in[6];
    const int*   tgt_idx      = (const int*)d_in[7];
    const int*   patch_idx    = (const int*)d_in[8];
    float*       out          = (float*)d_out;

    float* table = (float*)d_ws;                                    // 50.3 MB
    f32x4* pose8 = (f32x4*)((char*)d_ws + (size_t)E_NUM * 12);      // 256 KB

    pose_prep<<<(7 * P_NUM / 4) / 256, 256, 0, stream>>>(poses, init_poses, pose8, out);
    fuse_prep<<<(E_NUM / 4) / 256, 256, 0, stream>>>(patch_coords, elev, init_elev,
                                                     (f32x4*)table, out);

    const int block = 256;
    const int grid  = E_NUM / (block * EPT);    // 4096
    ba_main<<<grid, block, 0, stream>>>(table, pose8, target, src_idx, tgt_idx,
                                        patch_idx, out);
}